// Round 4
// baseline (1525.766 us; speedup 1.0000x reference)
//
#include <hip/hip_runtime.h>

// Sinkhorn in z-space, fp32 K/KT + fp64 state, ONE persistent cooperative
// kernel for all 50 iterations with a hand-rolled device-scope barrier.
//   row:  w_i = (1/4096) / (sum_j K_ij z_j + 2048*zpad)
//   col:  z_j = (1/4096) / (sum_i KT_ji w_i + 2048*wpad)
//   pads: wpad' = (1/4096)/(sum(z) + 2048*zpad)  (and symmetric), computed
//         REDUNDANTLY per block from its own staged copy (bitwise identical).
// Cross-block traffic (z/w, 16 KB/half-step) uses agent-scope atomics (LLC,
// coherent across XCDs). K/KT are read-only after build -> normal loads,
// L2-resident across all 100 sweeps (4 MB per XCD slice).

#define INV_N (1.0 / 4096.0)

// ---- scratch layout inside d_out (67,108,864 bytes) ----
#define OFF_K 0UL            // K  fp32 2048x2048
#define OFF_KT 16777216UL    // KT fp32 2048x2048
#define OFF_BAR 33554432UL   // barrier counter (dead once epilogue runs)
#define OFF_W 67059712UL     // w: 2048 fp64 = out row 4093
#define OFF_Z 67076096UL     // z: 2048 fp64 = out row 4094
#define OFF_SCAL 67092480UL  // scal[0]=wpad scal[1]=zpad = out row 4095 head

// fp64 exp (rel err ~3e-13 on [-20,0]).
static __device__ __forceinline__ double fexp(double x) {
  double t = x * 1.4426950408889634074;
  double n = rint(t);
  double r = fma(n, -0.69314718055994530942, x);
  double p = 2.7557319223985890653e-7;
  p = fma(p, r, 2.7557319223985890653e-6);
  p = fma(p, r, 2.4801587301587301587e-5);
  p = fma(p, r, 1.9841269841269841270e-4);
  p = fma(p, r, 1.3888888888888888889e-3);
  p = fma(p, r, 8.3333333333333333333e-3);
  p = fma(p, r, 4.1666666666666666667e-2);
  p = fma(p, r, 1.6666666666666666667e-1);
  p = fma(p, r, 0.5);
  p = fma(p, r, 1.0);
  p = fma(p, r, 1.0);
  long long bits = ((long long)(1023 + (int)n)) << 52;
  return p * __longlong_as_double(bits);
}

// Build K (fp32) + KT (fp32, LDS tile transpose) + init z=1, bar=0.
__global__ __launch_bounds__(256) void k_build(const float* __restrict__ C, char* base) {
  float* K = (float*)(base + OFF_K);
  float* KT = (float*)(base + OFF_KT);
  __shared__ float s_t[64][65];
  int b = blockIdx.x, tid = threadIdx.x;
  int ti = b >> 5, tj = b & 31;
  int r0 = tid >> 6, c = tid & 63;
#pragma unroll
  for (int k = 0; k < 16; ++k) {
    int r = r0 + 4 * k;
    int row = ti * 64 + r, col = tj * 64 + c;
    float f = (float)fexp(-20.0 * (double)C[(size_t)row * 2048 + col]);
    K[(size_t)row * 2048 + col] = f;
    s_t[r][c] = f;
  }
  __syncthreads();
#pragma unroll
  for (int k = 0; k < 16; ++k) {
    int r = r0 + 4 * k;
    KT[(size_t)(tj * 64 + r) * 2048 + ti * 64 + c] = s_t[c][r];
  }
  if (b == 0) {
    double* z = (double*)(base + OFF_Z);
    for (int t = tid; t < 2048; t += 256) z[t] = 1.0;
    if (tid == 0) *(unsigned long long*)(base + OFF_BAR) = 0ULL;
  }
}

// One half-step inside the persistent kernel. Returns the new pad for the
// OTHER side: padOut = INV_N/(sum(vin) + 2048*padIn). Ends with the
// device-scope barrier (target supplied by caller, monotone counter).
static __device__ __forceinline__ double half_persist(
    const float* __restrict__ M, const double* __restrict__ vin,
    double* __restrict__ vout, double padIn, double* s_v, double* s_red,
    unsigned long long* bar, unsigned long long target,
    int tid, int wv, int l, int b) {
  // stage vin -> LDS (agent-scope: bypasses stale per-XCD L2) + local sum
  double loc = 0.0;
#pragma unroll
  for (int q = 0; q < 4; ++q) {
    int j = tid + 512 * q;
    double v = __hip_atomic_load(vin + j, __ATOMIC_RELAXED, __HIP_MEMORY_SCOPE_AGENT);
    s_v[j] = v;
    loc += v;
  }
#pragma unroll
  for (int off = 32; off; off >>= 1) loc += __shfl_xor(loc, off, 64);
  if (l == 0) s_red[wv] = loc;
  __syncthreads();
  double S = ((s_red[0] + s_red[1]) + (s_red[2] + s_red[3])) +
             ((s_red[4] + s_red[5]) + (s_red[6] + s_red[7]));
  double padOut = INV_N / (S + 2048.0 * padIn);  // uniform, redundant per block

  // row sweep: wave wv owns row i = b*8+wv of M (fp32, L2-resident)
  int i = b * 8 + wv;
  const float4* Mr = (const float4*)(M + (size_t)i * 2048);
  const double2* zr = (const double2*)s_v;
  double a0 = 0, a1 = 0, a2 = 0, a3 = 0;
#pragma unroll
  for (int k = 0; k < 8; ++k) {
    float4 m = Mr[l + 64 * k];
    double2 z0 = zr[2 * (l + 64 * k)];
    double2 z1 = zr[2 * (l + 64 * k) + 1];
    a0 = fma((double)m.x, z0.x, a0);
    a1 = fma((double)m.y, z0.y, a1);
    a2 = fma((double)m.z, z1.x, a2);
    a3 = fma((double)m.w, z1.y, a3);
  }
  double acc = (a0 + a1) + (a2 + a3);
#pragma unroll
  for (int off = 32; off; off >>= 1) acc += __shfl_xor(acc, off, 64);
  if (l == 0) {
    double wi = INV_N / (acc + 2048.0 * padIn);
    __hip_atomic_store(vout + i, wi, __ATOMIC_RELAXED, __HIP_MEMORY_SCOPE_AGENT);
  }

  // barrier: __syncthreads drains vmcnt (agent stores are at LLC), then
  // one arrival per block + tid0 spin on the monotone counter.
  __syncthreads();
  if (tid == 0) {
    __hip_atomic_fetch_add(bar, 1ULL, __ATOMIC_RELEASE, __HIP_MEMORY_SCOPE_AGENT);
    while (__hip_atomic_load(bar, __ATOMIC_ACQUIRE, __HIP_MEMORY_SCOPE_AGENT) < target)
      __builtin_amdgcn_s_sleep(2);
  }
  __syncthreads();
  return padOut;
}

// Persistent loop: 256 blocks x 512 thr (wave per row), cooperative launch
// guarantees co-residency for the custom barrier.
__global__ __launch_bounds__(512, 2) void k_loop(char* base) {
  const float* K = (const float*)(base + OFF_K);
  const float* KT = (const float*)(base + OFF_KT);
  double* w = (double*)(base + OFF_W);
  double* z = (double*)(base + OFF_Z);
  double* scal = (double*)(base + OFF_SCAL);
  unsigned long long* bar = (unsigned long long*)(base + OFF_BAR);
  __shared__ double s_v[2048];
  __shared__ double s_red[8];
  int tid = threadIdx.x, b = blockIdx.x;
  int wv = tid >> 6, l = tid & 63;
  double zpad = 1.0, wpad = 0.0;
  unsigned long long target = 0;
  for (int t = 0; t < 50; ++t) {
    target += 256;
    wpad = half_persist(K, z, w, zpad, s_v, s_red, bar, target, tid, wv, l, b);
    target += 256;
    zpad = half_persist(KT, w, z, wpad, s_v, s_red, bar, target, tid, wv, l, b);
  }
  if (b == 0 && tid == 0) {
    scal[0] = wpad;
    scal[1] = zpad;
  }
}

// Output rows 0..2047: out_ij = 4096*min(w_i z_j exp(-20 C_ij), 1), fp64 exp.
__global__ __launch_bounds__(512) void k_out_top(const float* __restrict__ C, char* base) {
  const double* w = (const double*)(base + OFF_W);
  const double* z = (const double*)(base + OFF_Z);
  const double* scal = (const double*)(base + OFF_SCAL);
  float* out = (float*)base;
  __shared__ double s_z[2048];
  __shared__ double s_w[8];
  int tid = threadIdx.x, b = blockIdx.x;
  const double2* zg = (const double2*)z;
  ((double2*)s_z)[tid] = zg[tid];
  ((double2*)s_z)[tid + 512] = zg[tid + 512];
  if (tid < 8) s_w[tid] = w[b * 8 + tid];
  double zpad = scal[1];
  __syncthreads();
  int wv = tid >> 6, l = tid & 63;
  int i = b * 8 + wv;
  double wi = s_w[wv];
  const float4* Cr = (const float4*)(C + (size_t)i * 2048);
  const double2* zr = (const double2*)s_z;
  float* orow = out + (size_t)i * 4096;
#pragma unroll 2
  for (int k = 0; k < 8; ++k) {
    float4 cv = Cr[l + 64 * k];
    double2 z0 = zr[2 * (l + 64 * k)];
    double2 z1 = zr[2 * (l + 64 * k) + 1];
    float4 f;
    f.x = (float)(4096.0 * fmin(wi * z0.x * fexp(-20.0 * (double)cv.x), 1.0));
    f.y = (float)(4096.0 * fmin(wi * z0.y * fexp(-20.0 * (double)cv.y), 1.0));
    f.z = (float)(4096.0 * fmin(wi * z1.x * fexp(-20.0 * (double)cv.z), 1.0));
    f.w = (float)(4096.0 * fmin(wi * z1.y * fexp(-20.0 * (double)cv.w), 1.0));
    ((float4*)orow)[l + 64 * k] = f;
  }
  float cr = (float)(4096.0 * fmin(wi * zpad, 1.0));
  float4 fc;
  fc.x = cr; fc.y = cr; fc.z = cr; fc.w = cr;
#pragma unroll
  for (int k = 0; k < 8; ++k) ((float4*)(orow + 2048))[l + 64 * k] = fc;
}

// Output rows 2048..4092 (all identical).
__global__ __launch_bounds__(512) void k_out_bot(char* base) {
  const double* z = (const double*)(base + OFF_Z);
  const double* scal = (const double*)(base + OFF_SCAL);
  float* out = (float*)base;
  __shared__ float s_val[2048];
  int tid = threadIdx.x, b = blockIdx.x;
  double wpad = scal[0], zpad = scal[1];
  {
    int j = tid * 4;
    double2 z0 = ((const double2*)(z + j))[0];
    double2 z1 = ((const double2*)(z + j))[1];
    s_val[j + 0] = (float)(4096.0 * fmin(wpad * z0.x, 1.0));
    s_val[j + 1] = (float)(4096.0 * fmin(wpad * z0.y, 1.0));
    s_val[j + 2] = (float)(4096.0 * fmin(wpad * z1.x, 1.0));
    s_val[j + 3] = (float)(4096.0 * fmin(wpad * z1.y, 1.0));
  }
  float cf = (float)(4096.0 * fmin(wpad * zpad, 1.0));
  __syncthreads();
  int wv = tid >> 6, l = tid & 63;
  int row = 2048 + b * 8 + wv;
  if (row <= 4092) {
    float4* orow = (float4*)(out + (size_t)row * 4096);
    float4 fc;
    fc.x = cf; fc.y = cf; fc.z = cf; fc.w = cf;
#pragma unroll
    for (int k = 0; k < 8; ++k) orow[l + 64 * k] = ((const float4*)s_val)[l + 64 * k];
#pragma unroll
    for (int k = 0; k < 8; ++k) orow[512 + l + 64 * k] = fc;
  }
}

// Output rows 4093..4095 (overwrites the w/z/scal stash; single block, staged).
__global__ __launch_bounds__(512) void k_out_tail(char* base) {
  const double* z = (const double*)(base + OFF_Z);
  const double* scal = (const double*)(base + OFF_SCAL);
  float* out = (float*)base;
  __shared__ float s_val[2048];
  int tid = threadIdx.x;
  double wpad = scal[0], zpad = scal[1];
  {
    int j = tid * 4;
    double2 z0 = ((const double2*)(z + j))[0];
    double2 z1 = ((const double2*)(z + j))[1];
    s_val[j + 0] = (float)(4096.0 * fmin(wpad * z0.x, 1.0));
    s_val[j + 1] = (float)(4096.0 * fmin(wpad * z0.y, 1.0));
    s_val[j + 2] = (float)(4096.0 * fmin(wpad * z1.x, 1.0));
    s_val[j + 3] = (float)(4096.0 * fmin(wpad * z1.y, 1.0));
  }
  float cf = (float)(4096.0 * fmin(wpad * zpad, 1.0));
  __syncthreads();  // all reads of z/scal complete before writes below
  float4 fc;
  fc.x = cf; fc.y = cf; fc.z = cf; fc.w = cf;
  for (int row = 4093; row <= 4095; ++row) {
    float4* orow = (float4*)(out + (size_t)row * 4096);
    for (int t = tid; t < 1024; t += 512)
      orow[t] = (t < 512) ? ((const float4*)s_val)[t] : fc;
  }
}

extern "C" void kernel_launch(void* const* d_in, const int* in_sizes, int n_in,
                              void* d_out, int out_size, void* d_ws, size_t ws_size,
                              hipStream_t stream) {
  (void)in_sizes; (void)n_in; (void)d_ws; (void)ws_size; (void)out_size;
  const float* C = (const float*)d_in[0];
  char* base = (char*)d_out;
  k_build<<<1024, 256, 0, stream>>>(C, base);
  void* args[] = {(void*)&base};
  hipLaunchCooperativeKernel((void*)k_loop, dim3(256), dim3(512), args, 0, stream);
  k_out_top<<<256, 512, 0, stream>>>(C, base);
  k_out_bot<<<256, 512, 0, stream>>>(base);
  k_out_tail<<<1, 512, 0, stream>>>(base);
}

// Round 5
// 911.193 us; speedup vs baseline: 1.6745x; 1.6745x over previous
//
#include <hip/hip_runtime.h>

// Sinkhorn in z-space, fp32 K/KT + fp64 state, ONE persistent cooperative
// kernel with an ALL-RELAXED device-scope barrier.
//   row:  w_i = (1/4096) / (sum_j K_ij z_j + 2048*zpad)
//   col:  z_j = (1/4096) / (sum_i KT_ji w_i + 2048*wpad)
//   pads computed redundantly per block (bitwise identical).
// Cross-block data moves via RELAXED agent-scope atomics (plain global ops
// with coherence bits -> LLC; no buffer_wbl2/buffer_inv cache maintenance,
// which is what made acquire/release barriers cost ~13us in R4).
// Ordering: __syncthreads() drains each wave's vmcnt before s_barrier, so all
// vout stores are LLC-visible before the (relaxed) arrival fetch_add.

#define INV_N (1.0 / 4096.0)

// ---- scratch layout inside d_out (67,108,864 bytes) ----
#define OFF_K 0UL            // K  fp32 2048x2048
#define OFF_KT 16777216UL    // KT fp32 2048x2048
#define OFF_BAR 33554432UL   // barrier counter (u32), dead once epilogue runs
#define OFF_W 67059712UL     // w: 2048 fp64 = out row 4093
#define OFF_Z 67076096UL     // z: 2048 fp64 = out row 4094
#define OFF_SCAL 67092480UL  // scal[0]=wpad scal[1]=zpad = out row 4095 head

// fp64 exp (rel err ~3e-13 on [-20,0]).
static __device__ __forceinline__ double fexp(double x) {
  double t = x * 1.4426950408889634074;
  double n = rint(t);
  double r = fma(n, -0.69314718055994530942, x);
  double p = 2.7557319223985890653e-7;
  p = fma(p, r, 2.7557319223985890653e-6);
  p = fma(p, r, 2.4801587301587301587e-5);
  p = fma(p, r, 1.9841269841269841270e-4);
  p = fma(p, r, 1.3888888888888888889e-3);
  p = fma(p, r, 8.3333333333333333333e-3);
  p = fma(p, r, 4.1666666666666666667e-2);
  p = fma(p, r, 1.6666666666666666667e-1);
  p = fma(p, r, 0.5);
  p = fma(p, r, 1.0);
  p = fma(p, r, 1.0);
  long long bits = ((long long)(1023 + (int)n)) << 52;
  return p * __longlong_as_double(bits);
}

// Build K (fp32) + KT (fp32, LDS tile transpose) + init z=1, bar=0.
__global__ __launch_bounds__(256) void k_build(const float* __restrict__ C, char* base) {
  float* K = (float*)(base + OFF_K);
  float* KT = (float*)(base + OFF_KT);
  __shared__ float s_t[64][65];
  int b = blockIdx.x, tid = threadIdx.x;
  int ti = b >> 5, tj = b & 31;
  int r0 = tid >> 6, c = tid & 63;
#pragma unroll
  for (int k = 0; k < 16; ++k) {
    int r = r0 + 4 * k;
    int row = ti * 64 + r, col = tj * 64 + c;
    float f = (float)fexp(-20.0 * (double)C[(size_t)row * 2048 + col]);
    K[(size_t)row * 2048 + col] = f;
    s_t[r][c] = f;
  }
  __syncthreads();
#pragma unroll
  for (int k = 0; k < 16; ++k) {
    int r = r0 + 4 * k;
    KT[(size_t)(tj * 64 + r) * 2048 + ti * 64 + c] = s_t[c][r];
  }
  if (b == 0) {
    double* z = (double*)(base + OFF_Z);
    for (int t = tid; t < 2048; t += 256) z[t] = 1.0;
    if (tid == 0) *(unsigned int*)(base + OFF_BAR) = 0u;
  }
}

// One half-step. s_z is SoA: s_z[e][g] = vin[4g+e], plane stride 520 doubles
// (planes land on banks 0/16/0/16 -> 2-way max on both write and read = free).
static __device__ __forceinline__ double half_persist(
    const float* __restrict__ M, const double* __restrict__ vin,
    double* __restrict__ vout, double padIn, double (*s_z)[520], double* s_red,
    unsigned int* bar, unsigned int target, int tid, int wv, int l, int b) {
  // stage vin -> LDS (relaxed agent atomics: read fresh from LLC) + local sum
  double loc = 0.0;
#pragma unroll
  for (int q = 0; q < 4; ++q) {
    int j = tid + 512 * q;
    double v = __hip_atomic_load(vin + j, __ATOMIC_RELAXED, __HIP_MEMORY_SCOPE_AGENT);
    s_z[j & 3][j >> 2] = v;
    loc += v;
  }
#pragma unroll
  for (int off = 32; off; off >>= 1) loc += __shfl_xor(loc, off, 64);
  if (l == 0) s_red[wv] = loc;
  __syncthreads();
  double S = ((s_red[0] + s_red[1]) + (s_red[2] + s_red[3])) +
             ((s_red[4] + s_red[5]) + (s_red[6] + s_red[7]));
  double padOut = INV_N / (S + 2048.0 * padIn);  // uniform, redundant per block

  // row sweep: wave wv owns row i = b*8+wv of M (fp32, per-XCD L2-resident)
  int i = b * 8 + wv;
  const float4* Mr = (const float4*)(M + (size_t)i * 2048);
  double a0 = 0, a1 = 0, a2 = 0, a3 = 0;
#pragma unroll
  for (int k = 0; k < 8; ++k) {
    int g = l + 64 * k;
    float4 m = Mr[g];
    a0 = fma((double)m.x, s_z[0][g], a0);
    a1 = fma((double)m.y, s_z[1][g], a1);
    a2 = fma((double)m.z, s_z[2][g], a2);
    a3 = fma((double)m.w, s_z[3][g], a3);
  }
  double acc = (a0 + a1) + (a2 + a3);
#pragma unroll
  for (int off = 32; off; off >>= 1) acc += __shfl_xor(acc, off, 64);
  if (l == 0) {
    double wi = INV_N / (acc + 2048.0 * padIn);
    __hip_atomic_store(vout + i, wi, __ATOMIC_RELAXED, __HIP_MEMORY_SCOPE_AGENT);
  }

  // barrier: __syncthreads drains every wave's vmcnt (vout stores reach LLC),
  // then one RELAXED arrival per block + tid0 RELAXED spin. No cache ops.
  __syncthreads();
  if (tid == 0) {
    __hip_atomic_fetch_add(bar, 1u, __ATOMIC_RELAXED, __HIP_MEMORY_SCOPE_AGENT);
    while (__hip_atomic_load(bar, __ATOMIC_RELAXED, __HIP_MEMORY_SCOPE_AGENT) < target)
      __builtin_amdgcn_s_sleep(1);
  }
  __syncthreads();
  return padOut;
}

// Persistent loop: 256 blocks x 512 thr (wave per row), cooperative launch
// guarantees co-residency for the custom barrier.
__global__ __launch_bounds__(512, 2) void k_loop(char* base) {
  const float* K = (const float*)(base + OFF_K);
  const float* KT = (const float*)(base + OFF_KT);
  double* w = (double*)(base + OFF_W);
  double* z = (double*)(base + OFF_Z);
  double* scal = (double*)(base + OFF_SCAL);
  unsigned int* bar = (unsigned int*)(base + OFF_BAR);
  __shared__ double s_z[4][520];
  __shared__ double s_red[8];
  int tid = threadIdx.x, b = blockIdx.x;
  int wv = tid >> 6, l = tid & 63;
  double zpad = 1.0, wpad = 0.0;
  unsigned int target = 0;
  for (int t = 0; t < 50; ++t) {
    target += 256;
    wpad = half_persist(K, z, w, zpad, s_z, s_red, bar, target, tid, wv, l, b);
    target += 256;
    zpad = half_persist(KT, w, z, wpad, s_z, s_red, bar, target, tid, wv, l, b);
  }
  if (b == 0 && tid == 0) {
    scal[0] = wpad;
    scal[1] = zpad;
  }
}

// Output rows 0..2047: out_ij = 4096*min(w_i z_j exp(-20 C_ij), 1), fp64 exp.
__global__ __launch_bounds__(512) void k_out_top(const float* __restrict__ C, char* base) {
  const double* w = (const double*)(base + OFF_W);
  const double* z = (const double*)(base + OFF_Z);
  const double* scal = (const double*)(base + OFF_SCAL);
  float* out = (float*)base;
  __shared__ double s_z[2048];
  __shared__ double s_w[8];
  int tid = threadIdx.x, b = blockIdx.x;
  const double2* zg = (const double2*)z;
  ((double2*)s_z)[tid] = zg[tid];
  ((double2*)s_z)[tid + 512] = zg[tid + 512];
  if (tid < 8) s_w[tid] = w[b * 8 + tid];
  double zpad = scal[1];
  __syncthreads();
  int wv = tid >> 6, l = tid & 63;
  int i = b * 8 + wv;
  double wi = s_w[wv];
  const float4* Cr = (const float4*)(C + (size_t)i * 2048);
  const double2* zr = (const double2*)s_z;
  float* orow = out + (size_t)i * 4096;
#pragma unroll 2
  for (int k = 0; k < 8; ++k) {
    float4 cv = Cr[l + 64 * k];
    double2 z0 = zr[2 * (l + 64 * k)];
    double2 z1 = zr[2 * (l + 64 * k) + 1];
    float4 f;
    f.x = (float)(4096.0 * fmin(wi * z0.x * fexp(-20.0 * (double)cv.x), 1.0));
    f.y = (float)(4096.0 * fmin(wi * z0.y * fexp(-20.0 * (double)cv.y), 1.0));
    f.z = (float)(4096.0 * fmin(wi * z1.x * fexp(-20.0 * (double)cv.z), 1.0));
    f.w = (float)(4096.0 * fmin(wi * z1.y * fexp(-20.0 * (double)cv.w), 1.0));
    ((float4*)orow)[l + 64 * k] = f;
  }
  float cr = (float)(4096.0 * fmin(wi * zpad, 1.0));
  float4 fc;
  fc.x = cr; fc.y = cr; fc.z = cr; fc.w = cr;
#pragma unroll
  for (int k = 0; k < 8; ++k) ((float4*)(orow + 2048))[l + 64 * k] = fc;
}

// Output rows 2048..4092 (all identical).
__global__ __launch_bounds__(512) void k_out_bot(char* base) {
  const double* z = (const double*)(base + OFF_Z);
  const double* scal = (const double*)(base + OFF_SCAL);
  float* out = (float*)base;
  __shared__ float s_val[2048];
  int tid = threadIdx.x, b = blockIdx.x;
  double wpad = scal[0], zpad = scal[1];
  {
    int j = tid * 4;
    double2 z0 = ((const double2*)(z + j))[0];
    double2 z1 = ((const double2*)(z + j))[1];
    s_val[j + 0] = (float)(4096.0 * fmin(wpad * z0.x, 1.0));
    s_val[j + 1] = (float)(4096.0 * fmin(wpad * z0.y, 1.0));
    s_val[j + 2] = (float)(4096.0 * fmin(wpad * z1.x, 1.0));
    s_val[j + 3] = (float)(4096.0 * fmin(wpad * z1.y, 1.0));
  }
  float cf = (float)(4096.0 * fmin(wpad * zpad, 1.0));
  __syncthreads();
  int wv = tid >> 6, l = tid & 63;
  int row = 2048 + b * 8 + wv;
  if (row <= 4092) {
    float4* orow = (float4*)(out + (size_t)row * 4096);
    float4 fc;
    fc.x = cf; fc.y = cf; fc.z = cf; fc.w = cf;
#pragma unroll
    for (int k = 0; k < 8; ++k) orow[l + 64 * k] = ((const float4*)s_val)[l + 64 * k];
#pragma unroll
    for (int k = 0; k < 8; ++k) orow[512 + l + 64 * k] = fc;
  }
}

// Output rows 4093..4095 (overwrites the w/z/scal stash; single block, staged).
__global__ __launch_bounds__(512) void k_out_tail(char* base) {
  const double* z = (const double*)(base + OFF_Z);
  const double* scal = (const double*)(base + OFF_SCAL);
  float* out = (float*)base;
  __shared__ float s_val[2048];
  int tid = threadIdx.x;
  double wpad = scal[0], zpad = scal[1];
  {
    int j = tid * 4;
    double2 z0 = ((const double2*)(z + j))[0];
    double2 z1 = ((const double2*)(z + j))[1];
    s_val[j + 0] = (float)(4096.0 * fmin(wpad * z0.x, 1.0));
    s_val[j + 1] = (float)(4096.0 * fmin(wpad * z0.y, 1.0));
    s_val[j + 2] = (float)(4096.0 * fmin(wpad * z1.x, 1.0));
    s_val[j + 3] = (float)(4096.0 * fmin(wpad * z1.y, 1.0));
  }
  float cf = (float)(4096.0 * fmin(wpad * zpad, 1.0));
  __syncthreads();  // all reads of z/scal complete before writes below
  float4 fc;
  fc.x = cf; fc.y = cf; fc.z = cf; fc.w = cf;
  for (int row = 4093; row <= 4095; ++row) {
    float4* orow = (float4*)(out + (size_t)row * 4096);
    for (int t = tid; t < 1024; t += 512)
      orow[t] = (t < 512) ? ((const float4*)s_val)[t] : fc;
  }
}

extern "C" void kernel_launch(void* const* d_in, const int* in_sizes, int n_in,
                              void* d_out, int out_size, void* d_ws, size_t ws_size,
                              hipStream_t stream) {
  (void)in_sizes; (void)n_in; (void)d_ws; (void)ws_size; (void)out_size;
  const float* C = (const float*)d_in[0];
  char* base = (char*)d_out;
  k_build<<<1024, 256, 0, stream>>>(C, base);
  void* args[] = {(void*)&base};
  hipLaunchCooperativeKernel((void*)k_loop, dim3(256), dim3(512), args, 0, stream);
  k_out_top<<<256, 512, 0, stream>>>(C, base);
  k_out_bot<<<256, 512, 0, stream>>>(base);
  k_out_tail<<<1, 512, 0, stream>>>(base);
}

// Round 6
// 529.070 us; speedup vs baseline: 2.8839x; 1.7223x over previous
//
#include <hip/hip_runtime.h>

// Sinkhorn in z-space, fp32 K/KT + fp64 state, ONE persistent cooperative
// kernel. Device barrier = 2-level tree of RELAXED agent-scope RMWs on
// SEPARATE cache lines + load-only epoch broadcast.
//   R5 lesson: 256 relaxed fetch_adds on ONE LLC line serialize (~55cy each
//   ~= 6us). Tree: 32 RMWs/line on 8 parallel lines + 8 RMWs + 1 store.
//   Spinners poll the epoch word with plain loads (no line locking).
// Data exchange (z/w) via relaxed agent atomics (LLC-coherent, no cache
// maintenance). K/KT read-only after build -> per-XCD L2-resident all 100
// sweeps. Pads computed redundantly per block (bitwise identical).

#define INV_N (1.0 / 4096.0)

// ---- scratch layout inside d_out (67,108,864 bytes) ----
#define OFF_K 0UL            // K  fp32 2048x2048
#define OFF_KT 16777216UL    // KT fp32 2048x2048
#define OFF_BAR 33554432UL   // barrier block: 8 group ctrs @256B, mid, epoch
#define OFF_W 67059712UL     // w: 2048 fp64 = out row 4093
#define OFF_Z 67076096UL     // z: 2048 fp64 = out row 4094
#define OFF_SCAL 67092480UL  // scal[0]=wpad scal[1]=zpad = out row 4095 head

// fp64 exp (rel err ~3e-13 on [-20,0]).
static __device__ __forceinline__ double fexp(double x) {
  double t = x * 1.4426950408889634074;
  double n = rint(t);
  double r = fma(n, -0.69314718055994530942, x);
  double p = 2.7557319223985890653e-7;
  p = fma(p, r, 2.7557319223985890653e-6);
  p = fma(p, r, 2.4801587301587301587e-5);
  p = fma(p, r, 1.9841269841269841270e-4);
  p = fma(p, r, 1.3888888888888888889e-3);
  p = fma(p, r, 8.3333333333333333333e-3);
  p = fma(p, r, 4.1666666666666666667e-2);
  p = fma(p, r, 1.6666666666666666667e-1);
  p = fma(p, r, 0.5);
  p = fma(p, r, 1.0);
  p = fma(p, r, 1.0);
  long long bits = ((long long)(1023 + (int)n)) << 52;
  return p * __longlong_as_double(bits);
}

// Build K (fp32) + KT (fp32, LDS tile transpose) + init z=1 and barrier block.
__global__ __launch_bounds__(256) void k_build(const float* __restrict__ C, char* base) {
  float* K = (float*)(base + OFF_K);
  float* KT = (float*)(base + OFF_KT);
  __shared__ float s_t[64][65];
  int b = blockIdx.x, tid = threadIdx.x;
  int ti = b >> 5, tj = b & 31;
  int r0 = tid >> 6, c = tid & 63;
#pragma unroll
  for (int k = 0; k < 16; ++k) {
    int r = r0 + 4 * k;
    int row = ti * 64 + r, col = tj * 64 + c;
    float f = (float)fexp(-20.0 * (double)C[(size_t)row * 2048 + col]);
    K[(size_t)row * 2048 + col] = f;
    s_t[r][c] = f;
  }
  __syncthreads();
#pragma unroll
  for (int k = 0; k < 16; ++k) {
    int r = r0 + 4 * k;
    KT[(size_t)(tj * 64 + r) * 2048 + ti * 64 + c] = s_t[c][r];
  }
  if (b == 0) {
    double* z = (double*)(base + OFF_Z);
    for (int t = tid; t < 2048; t += 256) z[t] = 1.0;
    // zero 10 * 256B of barrier state (8 group ctrs, mid ctr, epoch)
    if (tid < 640) ((unsigned int*)(base + OFF_BAR))[tid] = 0u;
  }
}

// Tree barrier arrival + epoch wait. phase is 1-indexed.
static __device__ __forceinline__ void tree_barrier(char* base, int b, int tid,
                                                    unsigned int phase) {
  unsigned int* grp = (unsigned int*)(base + OFF_BAR) + (b >> 5) * 64;  // 256B apart
  unsigned int* mid = (unsigned int*)(base + OFF_BAR) + 8 * 64;
  unsigned int* epoch = (unsigned int*)(base + OFF_BAR) + 9 * 64;
  __syncthreads();  // drains vmcnt: this block's vout stores are LLC-visible
  if (tid == 0) {
    unsigned int o =
        __hip_atomic_fetch_add(grp, 1u, __ATOMIC_RELAXED, __HIP_MEMORY_SCOPE_AGENT);
    if (o == 32u * phase - 1u) {  // last of my 32-block group
      unsigned int o2 =
          __hip_atomic_fetch_add(mid, 1u, __ATOMIC_RELAXED, __HIP_MEMORY_SCOPE_AGENT);
      if (o2 == 8u * phase - 1u)  // last group overall -> broadcast
        __hip_atomic_store(epoch, phase, __ATOMIC_RELAXED, __HIP_MEMORY_SCOPE_AGENT);
    }
    while (__hip_atomic_load(epoch, __ATOMIC_RELAXED, __HIP_MEMORY_SCOPE_AGENT) < phase)
      __builtin_amdgcn_s_sleep(1);
  }
  __syncthreads();
}

// One half-step. s_z is SoA: s_z[e][g] = vin[4g+e], plane stride 520 doubles.
static __device__ __forceinline__ double half_persist(
    const float* __restrict__ M, const double* __restrict__ vin,
    double* __restrict__ vout, double padIn, double (*s_z)[520], double* s_red,
    char* base, unsigned int phase, int tid, int wv, int l, int b) {
  // stage vin -> LDS (relaxed agent atomics: fresh from LLC) + local sum
  double loc = 0.0;
#pragma unroll
  for (int q = 0; q < 4; ++q) {
    int j = tid + 512 * q;
    double v = __hip_atomic_load(vin + j, __ATOMIC_RELAXED, __HIP_MEMORY_SCOPE_AGENT);
    s_z[j & 3][j >> 2] = v;
    loc += v;
  }
#pragma unroll
  for (int off = 32; off; off >>= 1) loc += __shfl_xor(loc, off, 64);
  if (l == 0) s_red[wv] = loc;
  __syncthreads();
  double S = ((s_red[0] + s_red[1]) + (s_red[2] + s_red[3])) +
             ((s_red[4] + s_red[5]) + (s_red[6] + s_red[7]));
  double padOut = INV_N / (S + 2048.0 * padIn);  // uniform, redundant per block

  // row sweep: wave wv owns row i = b*8+wv of M (fp32, per-XCD L2-resident)
  int i = b * 8 + wv;
  const float4* Mr = (const float4*)(M + (size_t)i * 2048);
  double a0 = 0, a1 = 0, a2 = 0, a3 = 0;
#pragma unroll
  for (int k = 0; k < 8; ++k) {
    int g = l + 64 * k;
    float4 m = Mr[g];
    a0 = fma((double)m.x, s_z[0][g], a0);
    a1 = fma((double)m.y, s_z[1][g], a1);
    a2 = fma((double)m.z, s_z[2][g], a2);
    a3 = fma((double)m.w, s_z[3][g], a3);
  }
  double acc = (a0 + a1) + (a2 + a3);
#pragma unroll
  for (int off = 32; off; off >>= 1) acc += __shfl_xor(acc, off, 64);
  if (l == 0) {
    double wi = INV_N / (acc + 2048.0 * padIn);
    __hip_atomic_store(vout + i, wi, __ATOMIC_RELAXED, __HIP_MEMORY_SCOPE_AGENT);
  }
  tree_barrier(base, b, tid, phase);
  return padOut;
}

// Persistent loop: 256 blocks x 512 thr (wave per row), cooperative launch.
__global__ __launch_bounds__(512, 2) void k_loop(char* base) {
  const float* K = (const float*)(base + OFF_K);
  const float* KT = (const float*)(base + OFF_KT);
  double* w = (double*)(base + OFF_W);
  double* z = (double*)(base + OFF_Z);
  double* scal = (double*)(base + OFF_SCAL);
  __shared__ double s_z[4][520];
  __shared__ double s_red[8];
  int tid = threadIdx.x, b = blockIdx.x;
  int wv = tid >> 6, l = tid & 63;
  double zpad = 1.0, wpad = 0.0;
  unsigned int phase = 0;
  for (int t = 0; t < 50; ++t) {
    wpad = half_persist(K, z, w, zpad, s_z, s_red, base, ++phase, tid, wv, l, b);
    zpad = half_persist(KT, w, z, wpad, s_z, s_red, base, ++phase, tid, wv, l, b);
  }
  if (b == 0 && tid == 0) {
    scal[0] = wpad;
    scal[1] = zpad;
  }
}

// Output rows 0..2047: out_ij = 4096*min(w_i z_j exp(-20 C_ij), 1), fp64 exp.
__global__ __launch_bounds__(512) void k_out_top(const float* __restrict__ C, char* base) {
  const double* w = (const double*)(base + OFF_W);
  const double* z = (const double*)(base + OFF_Z);
  const double* scal = (const double*)(base + OFF_SCAL);
  float* out = (float*)base;
  __shared__ double s_z[2048];
  __shared__ double s_w[8];
  int tid = threadIdx.x, b = blockIdx.x;
  const double2* zg = (const double2*)z;
  ((double2*)s_z)[tid] = zg[tid];
  ((double2*)s_z)[tid + 512] = zg[tid + 512];
  if (tid < 8) s_w[tid] = w[b * 8 + tid];
  double zpad = scal[1];
  __syncthreads();
  int wv = tid >> 6, l = tid & 63;
  int i = b * 8 + wv;
  double wi = s_w[wv];
  const float4* Cr = (const float4*)(C + (size_t)i * 2048);
  const double2* zr = (const double2*)s_z;
  float* orow = out + (size_t)i * 4096;
#pragma unroll 2
  for (int k = 0; k < 8; ++k) {
    float4 cv = Cr[l + 64 * k];
    double2 z0 = zr[2 * (l + 64 * k)];
    double2 z1 = zr[2 * (l + 64 * k) + 1];
    float4 f;
    f.x = (float)(4096.0 * fmin(wi * z0.x * fexp(-20.0 * (double)cv.x), 1.0));
    f.y = (float)(4096.0 * fmin(wi * z0.y * fexp(-20.0 * (double)cv.y), 1.0));
    f.z = (float)(4096.0 * fmin(wi * z1.x * fexp(-20.0 * (double)cv.z), 1.0));
    f.w = (float)(4096.0 * fmin(wi * z1.y * fexp(-20.0 * (double)cv.w), 1.0));
    ((float4*)orow)[l + 64 * k] = f;
  }
  float cr = (float)(4096.0 * fmin(wi * zpad, 1.0));
  float4 fc;
  fc.x = cr; fc.y = cr; fc.z = cr; fc.w = cr;
#pragma unroll
  for (int k = 0; k < 8; ++k) ((float4*)(orow + 2048))[l + 64 * k] = fc;
}

// Output rows 2048..4092 (all identical).
__global__ __launch_bounds__(512) void k_out_bot(char* base) {
  const double* z = (const double*)(base + OFF_Z);
  const double* scal = (const double*)(base + OFF_SCAL);
  float* out = (float*)base;
  __shared__ float s_val[2048];
  int tid = threadIdx.x, b = blockIdx.x;
  double wpad = scal[0], zpad = scal[1];
  {
    int j = tid * 4;
    double2 z0 = ((const double2*)(z + j))[0];
    double2 z1 = ((const double2*)(z + j))[1];
    s_val[j + 0] = (float)(4096.0 * fmin(wpad * z0.x, 1.0));
    s_val[j + 1] = (float)(4096.0 * fmin(wpad * z0.y, 1.0));
    s_val[j + 2] = (float)(4096.0 * fmin(wpad * z1.x, 1.0));
    s_val[j + 3] = (float)(4096.0 * fmin(wpad * z1.y, 1.0));
  }
  float cf = (float)(4096.0 * fmin(wpad * zpad, 1.0));
  __syncthreads();
  int wv = tid >> 6, l = tid & 63;
  int row = 2048 + b * 8 + wv;
  if (row <= 4092) {
    float4* orow = (float4*)(out + (size_t)row * 4096);
    float4 fc;
    fc.x = cf; fc.y = cf; fc.z = cf; fc.w = cf;
#pragma unroll
    for (int k = 0; k < 8; ++k) orow[l + 64 * k] = ((const float4*)s_val)[l + 64 * k];
#pragma unroll
    for (int k = 0; k < 8; ++k) orow[512 + l + 64 * k] = fc;
  }
}

// Output rows 4093..4095 (overwrites the w/z/scal stash; single block, staged).
__global__ __launch_bounds__(512) void k_out_tail(char* base) {
  const double* z = (const double*)(base + OFF_Z);
  const double* scal = (const double*)(base + OFF_SCAL);
  float* out = (float*)base;
  __shared__ float s_val[2048];
  int tid = threadIdx.x;
  double wpad = scal[0], zpad = scal[1];
  {
    int j = tid * 4;
    double2 z0 = ((const double2*)(z + j))[0];
    double2 z1 = ((const double2*)(z + j))[1];
    s_val[j + 0] = (float)(4096.0 * fmin(wpad * z0.x, 1.0));
    s_val[j + 1] = (float)(4096.0 * fmin(wpad * z0.y, 1.0));
    s_val[j + 2] = (float)(4096.0 * fmin(wpad * z1.x, 1.0));
    s_val[j + 3] = (float)(4096.0 * fmin(wpad * z1.y, 1.0));
  }
  float cf = (float)(4096.0 * fmin(wpad * zpad, 1.0));
  __syncthreads();  // all reads of z/scal complete before writes below
  float4 fc;
  fc.x = cf; fc.y = cf; fc.z = cf; fc.w = cf;
  for (int row = 4093; row <= 4095; ++row) {
    float4* orow = (float4*)(out + (size_t)row * 4096);
    for (int t = tid; t < 1024; t += 512)
      orow[t] = (t < 512) ? ((const float4*)s_val)[t] : fc;
  }
}

extern "C" void kernel_launch(void* const* d_in, const int* in_sizes, int n_in,
                              void* d_out, int out_size, void* d_ws, size_t ws_size,
                              hipStream_t stream) {
  (void)in_sizes; (void)n_in; (void)d_ws; (void)ws_size; (void)out_size;
  const float* C = (const float*)d_in[0];
  char* base = (char*)d_out;
  k_build<<<1024, 256, 0, stream>>>(C, base);
  void* args[] = {(void*)&base};
  hipLaunchCooperativeKernel((void*)k_loop, dim3(256), dim3(512), args, 0, stream);
  k_out_top<<<256, 512, 0, stream>>>(C, base);
  k_out_bot<<<256, 512, 0, stream>>>(base);
  k_out_tail<<<1, 512, 0, stream>>>(base);
}